// Round 13
// baseline (632.169 us; speedup 1.0000x reference)
//
#include <hip/hip_runtime.h>

typedef short bf16x8 __attribute__((ext_vector_type(8)));
typedef float f32x4 __attribute__((ext_vector_type(4)));

static __device__ __forceinline__ unsigned short f2bf(float f) {
  unsigned u = __builtin_bit_cast(unsigned, f);
  u += 0x7FFFu + ((u >> 16) & 1u);   // round-nearest-even to bf16
  return (unsigned short)(u >> 16);
}

static __device__ __forceinline__ bf16x8 pack8s(const float* p, float s) {
  float4 a = *(const float4*)p;
  float4 b = *(const float4*)(p + 4);
  bf16x8 r;
  r[0] = (short)f2bf(a.x * s); r[1] = (short)f2bf(a.y * s);
  r[2] = (short)f2bf(a.z * s); r[3] = (short)f2bf(a.w * s);
  r[4] = (short)f2bf(b.x * s); r[5] = (short)f2bf(b.y * s);
  r[6] = (short)f2bf(b.z * s); r[7] = (short)f2bf(b.w * s);
  return r;
}

#define NLOG2E -1.442695040888963f
#define N2LOG2E -2.885390081777927f

// ---------------- LayerNorm (+ fused pw->bf16 prep): x[B,C,H,W] f32 -> xn[B,HW,C] bf16 ----------------
__global__ __launch_bounds__(512, 2) void ln_kernel(
    const float* __restrict__ x, const float* __restrict__ lg,
    const float* __restrict__ lb, unsigned short* __restrict__ xn,
    const float* __restrict__ pw, unsigned short* __restrict__ pwb) {
  __shared__ __align__(16) unsigned char slds[35840];
  float* mu_s = (float*)(slds + 34816);
  float* rs_s = (float*)(slds + 35328);
  const int tid = threadIdx.x;
  const int bid = blockIdx.x;
  if (bid < 128) {  // fused one-time pw f32 -> bf16 (65536 elems)
    const int i = bid * 512 + tid;
    pwb[i] = f2bf(pw[i]);
  }
  const int b = bid >> 5;
  const int hw0 = (bid & 31) << 7;
  const int q = tid >> 5, slot = tid & 31;
  const int lane = tid & 63, wv = tid >> 6;

  const float* xbase = x + ((size_t)b * 128) * 4096 + hw0 + (slot << 2);
  float4 xv[8];
#pragma unroll
  for (int p = 0; p < 8; ++p)
    xv[p] = *(const float4*)(xbase + (size_t)(q * 8 + p) * 4096);

  float s1[4] = {0.f, 0.f, 0.f, 0.f}, s2[4] = {0.f, 0.f, 0.f, 0.f};
#pragma unroll
  for (int p = 0; p < 8; ++p) {
    s1[0] += xv[p].x; s2[0] = fmaf(xv[p].x, xv[p].x, s2[0]);
    s1[1] += xv[p].y; s2[1] = fmaf(xv[p].y, xv[p].y, s2[1]);
    s1[2] += xv[p].z; s2[2] = fmaf(xv[p].z, xv[p].z, s2[2]);
    s1[3] += xv[p].w; s2[3] = fmaf(xv[p].w, xv[p].w, s2[3]);
  }
#pragma unroll
  for (int j = 0; j < 4; ++j) {
    s1[j] += __shfl_xor(s1[j], 32);
    s2[j] += __shfl_xor(s2[j], 32);
  }
  if (lane < 32) {
    float* psp = (float*)(slds + (wv * 32 + slot) * 36);
#pragma unroll
    for (int j = 0; j < 4; ++j) { psp[j] = s1[j]; psp[4 + j] = s2[j]; }
  }
  __syncthreads();
  if (tid < 128) {
    const int sl2 = tid >> 2, j2 = tid & 3;
    float a1 = 0.f, a2 = 0.f;
#pragma unroll
    for (int w = 0; w < 8; ++w) {
      const float* psp = (const float*)(slds + (w * 32 + sl2) * 36);
      a1 += psp[j2]; a2 += psp[4 + j2];
    }
    const float mu = a1 * 0.0078125f;
    const float var = a2 * 0.0078125f - mu * mu;
    mu_s[tid] = mu;
    rs_s[tid] = rsqrtf(var + 1e-5f);
  }
  __syncthreads();

  float lgv[8], lbv[8];
#pragma unroll
  for (int p = 0; p < 8; ++p) { lgv[p] = lg[q * 8 + p]; lbv[p] = lb[q * 8 + p]; }
#pragma unroll
  for (int j = 0; j < 4; ++j) {
    const int pos = (slot << 2) + j;
    const float mu = mu_s[pos], rs = rs_s[pos];
    float y[8];
#pragma unroll
    for (int p = 0; p < 8; ++p) {
      const float xvj = j == 0 ? xv[p].x : j == 1 ? xv[p].y : j == 2 ? xv[p].z : xv[p].w;
      y[p] = (xvj - mu) * rs * lgv[p] + lbv[p];
    }
    unsigned h0, h1, h2, h3;
    asm("v_cvt_pk_bf16_f32 %0, %1, %2" : "=v"(h0) : "v"(y[0]), "v"(y[1]));
    asm("v_cvt_pk_bf16_f32 %0, %1, %2" : "=v"(h1) : "v"(y[2]), "v"(y[3]));
    asm("v_cvt_pk_bf16_f32 %0, %1, %2" : "=v"(h2) : "v"(y[4]), "v"(y[5]));
    asm("v_cvt_pk_bf16_f32 %0, %1, %2" : "=v"(h3) : "v"(y[6]), "v"(y[7]));
    uint4 v; v.x = h0; v.y = h1; v.z = h2; v.w = h3;
    *(uint4*)(slds + pos * 272 + (q << 4)) = v;
  }
  __syncthreads();
#pragma unroll
  for (int it = 0; it < 4; ++it) {
    const int idx = (it << 9) + tid;
    const int row = idx >> 4, g = idx & 15;
    uint4 v = *(const uint4*)(slds + row * 272 + (g << 4));
    *(uint4*)((unsigned char*)xn + ((size_t)(b * 4096 + hw0 + row)) * 256 + (g << 4)) = v;
  }
}

// ---------------- Persistent bidirectional GRU scan ----------------
// N=8 two-block variant: 512 blocks x 512 thr; each block owns 8 sequences
// (half a group), per-wave structure identical to r10 (16 gate-cols, 128
// VGPR). LDS 8KB/block -> 2 blocks/CU, 4 waves/SIMD: two INDEPENDENT barrier
// domains per CU so the blocks' MFMA/VALU/LDS phases overlap (breaks the
// lockstep pipe serialization). MFMA N-lanes l15>=8 duplicate cols 0-7;
// h-writes/cat stores masked to l15<8.
// LDS: xbufA @0 (2KB), xbufB @2048, hbufA @4096, hbufB @6144.
__global__ __launch_bounds__(512, 4) void scan_kernel(
    const unsigned short* __restrict__ xn, unsigned short* __restrict__ cat,
    const float* __restrict__ wih0, const float* __restrict__ whh0,
    const float* __restrict__ bih0, const float* __restrict__ bhh0,
    const float* __restrict__ wih1, const float* __restrict__ whh1,
    const float* __restrict__ bih1, const float* __restrict__ bhh1,
    const float* __restrict__ wih2, const float* __restrict__ whh2,
    const float* __restrict__ bih2, const float* __restrict__ bhh2,
    const float* __restrict__ wih3, const float* __restrict__ whh3,
    const float* __restrict__ bih3, const float* __restrict__ bhh3) {
  __shared__ __align__(16) unsigned char lds[8192];
  const int tid = threadIdx.x;
  const int bid = blockIdx.x;
  const int dir = bid >> 7;
  const int grp = bid & 127;
  const int fwd = !(dir & 1);
  const int vert = dir >> 1;
  const int b = grp >> 3;
  const int r0 = (grp & 7) << 3;   // 8-sequence group
  const int wv = tid >> 6;
  const int lane = tid & 63;
  const int l15 = lane & 15;
  const int l7 = lane & 7;
  const int l4 = lane >> 4;

  const float* wih = dir == 0 ? wih0 : dir == 1 ? wih1 : dir == 2 ? wih2 : wih3;
  const float* whh = dir == 0 ? whh0 : dir == 1 ? whh1 : dir == 2 ? whh2 : whh3;
  const float* bih = dir == 0 ? bih0 : dir == 1 ? bih1 : dir == 2 ? bih2 : bih3;
  const float* bhh = dir == 0 ? bhh0 : dir == 1 ? bhh1 : dir == 2 ? bhh2 : bhh3;

  const int ca = (wv << 4) + l15;
  bf16x8 wf[3][2][4];
#pragma unroll
  for (int g = 0; g < 3; ++g) {
    const float sc = g == 2 ? N2LOG2E : NLOG2E;
#pragma unroll
    for (int s = 0; s < 2; ++s) {
      const float* Wp = s ? whh : wih;
#pragma unroll
      for (int kc = 0; kc < 4; ++kc)
        wf[g][s][kc] = pack8s(Wp + (size_t)((g << 7) + ca) * 128 + (kc << 5) + (l4 << 3), sc);
    }
  }
  const int cb = (wv << 4) + (l4 << 2);
  f32x4 br4, bz4, bnx4, bnh4;
  {
    float4 a = *(const float4*)(bih + cb), b2 = *(const float4*)(bhh + cb);
    br4[0] = (a.x + b2.x) * NLOG2E; br4[1] = (a.y + b2.y) * NLOG2E;
    br4[2] = (a.z + b2.z) * NLOG2E; br4[3] = (a.w + b2.w) * NLOG2E;
    a = *(const float4*)(bih + 128 + cb); b2 = *(const float4*)(bhh + 128 + cb);
    bz4[0] = (a.x + b2.x) * NLOG2E; bz4[1] = (a.y + b2.y) * NLOG2E;
    bz4[2] = (a.z + b2.z) * NLOG2E; bz4[3] = (a.w + b2.w) * NLOG2E;
    a = *(const float4*)(bih + 256 + cb);
    bnx4[0] = a.x * N2LOG2E; bnx4[1] = a.y * N2LOG2E;
    bnx4[2] = a.z * N2LOG2E; bnx4[3] = a.w * N2LOG2E;
    b2 = *(const float4*)(bhh + 256 + cb);
    bnh4[0] = b2.x * N2LOG2E; bnh4[1] = b2.y * N2LOG2E;
    bnh4[2] = b2.z * N2LOG2E; bnh4[3] = b2.w * N2LOG2E;
  }

  // Staging: threads 0..127 own (row ss = tid>>4 in [0,8), 16B chunk ck).
  const int ss = tid >> 4, ck = tid & 15;
  const unsigned char* xsp =
      (const unsigned char*)xn +
      (vert ? ((size_t)b << 20) + (size_t)(r0 + ss) * 256 + (ck << 4)
            : ((size_t)(b * 64 + r0 + ss) << 14) + (ck << 4));
  const int xstep = vert ? 16384 : 256;
  const int sdst = (ss * 256 + (ck << 4)) ^ ((ss & 7) << 4);

  const int seq = r0 + l7;
  const int cstep = vert ? 65536 : 1024;
  unsigned char* catp =
      (unsigned char*)cat +
      ((size_t)b * 4096 + (size_t)(vert ? seq : seq * 64)) * 1024 + dir * 256 + (cb << 1) +
      (size_t)(fwd ? 0 : 63) * cstep;
  const int cdelta = fwd ? cstep : -cstep;

  // zero hbufA (@4096, 2KB)
  if (tid < 256) *(unsigned long long*)(lds + 4096 + tid * 8) = 0ull;
  f32x4 hst = {0.f, 0.f, 0.f, 0.f};

  uint4 sX, sY;
  f32x4 grA, gzA, gnxA, grB, gzB, gnxB;
  {
    const unsigned char* xlq =
        (const unsigned char*)xn +
        (vert ? ((size_t)b << 20) + (size_t)(fwd ? 0 : 63) * 16384 + (size_t)seq * 256
              : ((size_t)(b * 64 + seq) << 14) + (size_t)(fwd ? 0 : 63) * 256) +
        (l4 << 4);
    bf16x8 x0[4];
#pragma unroll
    for (int kc = 0; kc < 4; ++kc) x0[kc] = *(const bf16x8*)(xlq + (kc << 6));
    uint4 s1v;
    if (tid < 128) {
      s1v = *(const uint4*)(xsp + (fwd ? 1 : 62) * xstep);
      sX = *(const uint4*)(xsp + (fwd ? 2 : 61) * xstep);
    }
    grA = br4; gzA = bz4; gnxA = bnx4;
#pragma unroll
    for (int kc = 0; kc < 4; ++kc) {
      grA = __builtin_amdgcn_mfma_f32_16x16x32_bf16(wf[0][0][kc], x0[kc], grA, 0, 0, 0);
      gzA = __builtin_amdgcn_mfma_f32_16x16x32_bf16(wf[1][0][kc], x0[kc], gzA, 0, 0, 0);
      gnxA = __builtin_amdgcn_mfma_f32_16x16x32_bf16(wf[2][0][kc], x0[kc], gnxA, 0, 0, 0);
    }
    if (tid < 128) *(uint4*)(lds + 2048 + sdst) = s1v;
  }
  __syncthreads();

#define STEP(TT, HCUR, HNXT, XRD, XWR, XW, XL, GRC, GZC, GNXC, GRN, GZN, GNXN)  \
  {                                                                             \
    bf16x8 ha[4], xa[4];                                                        \
    _Pragma("unroll")                                                           \
    for (int kc = 0; kc < 4; ++kc) {                                            \
      const int base = (l7 * 256 + (kc << 6) + (l4 << 4)) ^ (l7 << 4);          \
      ha[kc] = *(const bf16x8*)(lds + (HCUR) + base);                           \
      xa[kc] = *(const bf16x8*)(lds + (XRD) + base);                            \
    }                                                                           \
    if (tid < 128) {                                                            \
      *(uint4*)(lds + (XWR) + sdst) = XW;                                       \
      const int tl = (TT) + 3 > 63 ? 63 : (TT) + 3;                             \
      XL = *(const uint4*)(xsp + (fwd ? tl : 63 - tl) * xstep);                 \
    }                                                                           \
    f32x4 rh = {0.f, 0.f, 0.f, 0.f}, zh = {0.f, 0.f, 0.f, 0.f}, nh = bnh4;     \
    _Pragma("unroll")                                                           \
    for (int kc = 0; kc < 4; ++kc) {                                            \
      rh = __builtin_amdgcn_mfma_f32_16x16x32_bf16(wf[0][1][kc], ha[kc], rh, 0, 0, 0); \
      zh = __builtin_amdgcn_mfma_f32_16x16x32_bf16(wf[1][1][kc], ha[kc], zh, 0, 0, 0); \
      nh = __builtin_amdgcn_mfma_f32_16x16x32_bf16(wf[2][1][kc], ha[kc], nh, 0, 0, 0); \
    }                                                                           \
    GRN = br4; GZN = bz4; GNXN = bnx4;                                          \
    _Pragma("unroll")                                                           \
    for (int kc = 0; kc < 4; ++kc) {                                            \
      GRN = __builtin_amdgcn_mfma_f32_16x16x32_bf16(wf[0][0][kc], xa[kc], GRN, 0, 0, 0); \
      GZN = __builtin_amdgcn_mfma_f32_16x16x32_bf16(wf[1][0][kc], xa[kc], GZN, 0, 0, 0); \
      GNXN = __builtin_amdgcn_mfma_f32_16x16x32_bf16(wf[2][0][kc], xa[kc], GNXN, 0, 0, 0); \
    }                                                                           \
    f32x4 hnew;                                                                 \
    _Pragma("unroll")                                                           \
    for (int r = 0; r < 4; ++r) {                                               \
      const float er = __builtin_amdgcn_exp2f(GRC[r] + rh[r]);                  \
      const float rr = __builtin_amdgcn_rcpf(1.f + er);                         \
      const float ez = __builtin_amdgcn_exp2f(GZC[r] + zh[r]);                  \
      const float zz = __builtin_amdgcn_rcpf(1.f + ez);                         \
      const float pre = GNXC[r] + rr * nh[r];                                   \
      const float e2 = __builtin_amdgcn_exp2f(pre);                             \
      const float nn = fmaf(2.f, __builtin_amdgcn_rcpf(1.f + e2), -1.f);        \
      hnew[r] = nn + zz * (hst[r] - nn);                                        \
    }                                                                           \
    hst = hnew;                                                                 \
    unsigned hp0, hp1;                                                          \
    asm("v_cvt_pk_bf16_f32 %0, %1, %2" : "=v"(hp0) : "v"(hnew[0]), "v"(hnew[1])); \
    asm("v_cvt_pk_bf16_f32 %0, %1, %2" : "=v"(hp1) : "v"(hnew[2]), "v"(hnew[3])); \
    if (l15 < 8) {                                                              \
      unsigned long long hp = (unsigned long long)hp0 | ((unsigned long long)hp1 << 32); \
      *(unsigned long long*)(lds + (HNXT) + ((l7 * 256 + (cb << 1)) ^ (l7 << 4))) = hp; \
      uint2 v; v.x = hp0; v.y = hp1;                                            \
      *(uint2*)catp = v;                                                        \
    }                                                                           \
    catp += cdelta;                                                             \
    asm volatile("s_waitcnt lgkmcnt(0)" ::: "memory");                          \
    __builtin_amdgcn_s_barrier();                                               \
    asm volatile("" ::: "memory");                                              \
  }

  for (int tt2 = 0; tt2 < 64; tt2 += 2) {
    STEP(tt2, 4096, 6144, 2048, 0, sX, sY, grA, gzA, gnxA, grB, gzB, gnxB);
    STEP(tt2 + 1, 6144, 4096, 0, 2048, sY, sX, grB, gzB, gnxB, grA, gzA, gnxA);
  }
#undef STEP
}

// ---------------- Projection: out = cat[65536,512] @ pwb^T + pb + x ----------------
__global__ __launch_bounds__(512, 4) void proj_kernel(
    const unsigned short* __restrict__ cat, const unsigned short* __restrict__ pwb,
    const float* __restrict__ pb, const float* __restrict__ x,
    float* __restrict__ out) {
  __shared__ __align__(16) unsigned char lds[33280];
  const int tid = threadIdx.x;
  const int bid = blockIdx.x;
  const int row0 = bid << 6;
  const int b = row0 >> 12;
  const int hw0 = row0 & 4095;
  const int wv = tid >> 6, lane = tid & 63, l15 = lane & 15, l4 = lane >> 4;

  const int cc = (wv << 4) + l15;
  bf16x8 wfr[16];
#pragma unroll
  for (int kc = 0; kc < 16; ++kc)
    wfr[kc] = *(const bf16x8*)(pwb + (size_t)cc * 512 + (kc << 5) + (l4 << 3));
  const float pbv = pb[cc];

  f32x4 acc[4];
#pragma unroll
  for (int mt = 0; mt < 4; ++mt) acc[mt] = {pbv, pbv, pbv, pbv};

#pragma unroll
  for (int s = 0; s < 2; ++s) {
#pragma unroll
    for (int it = 0; it < 4; ++it) {
      const int item = tid + (it << 9);
      const int rr = item >> 6, ckk = item & 63;
      uint4 v = *(const uint4*)((const unsigned char*)cat +
                                ((size_t)(row0 + (s << 5) + rr)) * 1024 + ckk * 16);
      *(uint4*)(lds + rr * 1024 + ((ckk ^ (rr & 7)) << 4)) = v;
    }
    __syncthreads();
#pragma unroll
    for (int mh = 0; mh < 2; ++mh) {
      const int mt = (s << 1) + mh;
      const int rl = (mh << 4) + l15;
#pragma unroll
      for (int kc = 0; kc < 16; ++kc) {
        bf16x8 af =
            *(const bf16x8*)(lds + rl * 1024 + ((((kc << 2) + l4) ^ (rl & 7)) << 4));
        acc[mt] = __builtin_amdgcn_mfma_f32_16x16x32_bf16(af, wfr[kc], acc[mt], 0, 0, 0);
      }
    }
    __syncthreads();
  }

#pragma unroll
  for (int mt = 0; mt < 4; ++mt)
#pragma unroll
    for (int j = 0; j < 4; ++j)
      *(float*)(lds + cc * 260 + (((mt << 4) + (l4 << 2) + j) << 2)) = acc[mt][j];
  __syncthreads();
#pragma unroll
  for (int it = 0; it < 16; ++it) {
    const int c = (wv << 4) + it;
    const float v = *(const float*)(lds + c * 260 + (lane << 2));
    const size_t off = (size_t)(b * 128 + c) * 4096 + hw0 + lane;
    out[off] = v + x[off];
  }
}

extern "C" void kernel_launch(void* const* d_in, const int* in_sizes, int n_in,
                              void* d_out, int out_size, void* d_ws, size_t ws_size,
                              hipStream_t stream) {
  const float* x = (const float*)d_in[0];
  const float* lg = (const float*)d_in[1];
  const float* lb = (const float*)d_in[2];
  unsigned short* xn = (unsigned short*)d_ws;                       // 16.8 MB
  unsigned short* cat =
      (unsigned short*)((unsigned char*)d_ws + 16777216);           // 67.1 MB
  unsigned short* pwb =
      (unsigned short*)((unsigned char*)d_ws + 16777216 + 67108864);  // 128 KB

  ln_kernel<<<512, 512, 0, stream>>>(x, lg, lb, xn, (const float*)d_in[19], pwb);
  scan_kernel<<<512, 512, 0, stream>>>(
      xn, cat,
      (const float*)d_in[3], (const float*)d_in[4], (const float*)d_in[5], (const float*)d_in[6],
      (const float*)d_in[7], (const float*)d_in[8], (const float*)d_in[9], (const float*)d_in[10],
      (const float*)d_in[11], (const float*)d_in[12], (const float*)d_in[13], (const float*)d_in[14],
      (const float*)d_in[15], (const float*)d_in[16], (const float*)d_in[17], (const float*)d_in[18]);
  proj_kernel<<<1024, 512, 0, stream>>>(cat, pwb, (const float*)d_in[20], x,
                                        (float*)d_out);
}

// Round 14
// 173.191 us; speedup vs baseline: 3.6501x; 3.6501x over previous
//
#include <hip/hip_runtime.h>

typedef short bf16x8 __attribute__((ext_vector_type(8)));
typedef float f32x4 __attribute__((ext_vector_type(4)));

static __device__ __forceinline__ unsigned short f2bf(float f) {
  unsigned u = __builtin_bit_cast(unsigned, f);
  u += 0x7FFFu + ((u >> 16) & 1u);   // round-nearest-even to bf16
  return (unsigned short)(u >> 16);
}

static __device__ __forceinline__ bf16x8 pack8s(const float* p, float s) {
  float4 a = *(const float4*)p;
  float4 b = *(const float4*)(p + 4);
  bf16x8 r;
  r[0] = (short)f2bf(a.x * s); r[1] = (short)f2bf(a.y * s);
  r[2] = (short)f2bf(a.z * s); r[3] = (short)f2bf(a.w * s);
  r[4] = (short)f2bf(b.x * s); r[5] = (short)f2bf(b.y * s);
  r[6] = (short)f2bf(b.z * s); r[7] = (short)f2bf(b.w * s);
  return r;
}

#define NLOG2E -1.442695040888963f
#define N2LOG2E -2.885390081777927f

// ---------------- LayerNorm (+ fused pw->bf16 prep): x[B,C,H,W] f32 -> xn[B,HW,C] bf16 ----------------
__global__ __launch_bounds__(512, 2) void ln_kernel(
    const float* __restrict__ x, const float* __restrict__ lg,
    const float* __restrict__ lb, unsigned short* __restrict__ xn,
    const float* __restrict__ pw, unsigned short* __restrict__ pwb) {
  __shared__ __align__(16) unsigned char slds[35840];
  float* mu_s = (float*)(slds + 34816);
  float* rs_s = (float*)(slds + 35328);
  const int tid = threadIdx.x;
  const int bid = blockIdx.x;
  if (bid < 128) {  // fused one-time pw f32 -> bf16 (65536 elems)
    const int i = bid * 512 + tid;
    pwb[i] = f2bf(pw[i]);
  }
  const int b = bid >> 5;
  const int hw0 = (bid & 31) << 7;
  const int q = tid >> 5, slot = tid & 31;
  const int lane = tid & 63, wv = tid >> 6;

  const float* xbase = x + ((size_t)b * 128) * 4096 + hw0 + (slot << 2);
  float4 xv[8];
#pragma unroll
  for (int p = 0; p < 8; ++p)
    xv[p] = *(const float4*)(xbase + (size_t)(q * 8 + p) * 4096);

  float s1[4] = {0.f, 0.f, 0.f, 0.f}, s2[4] = {0.f, 0.f, 0.f, 0.f};
#pragma unroll
  for (int p = 0; p < 8; ++p) {
    s1[0] += xv[p].x; s2[0] = fmaf(xv[p].x, xv[p].x, s2[0]);
    s1[1] += xv[p].y; s2[1] = fmaf(xv[p].y, xv[p].y, s2[1]);
    s1[2] += xv[p].z; s2[2] = fmaf(xv[p].z, xv[p].z, s2[2]);
    s1[3] += xv[p].w; s2[3] = fmaf(xv[p].w, xv[p].w, s2[3]);
  }
#pragma unroll
  for (int j = 0; j < 4; ++j) {
    s1[j] += __shfl_xor(s1[j], 32);
    s2[j] += __shfl_xor(s2[j], 32);
  }
  if (lane < 32) {
    float* psp = (float*)(slds + (wv * 32 + slot) * 36);
#pragma unroll
    for (int j = 0; j < 4; ++j) { psp[j] = s1[j]; psp[4 + j] = s2[j]; }
  }
  __syncthreads();
  if (tid < 128) {
    const int sl2 = tid >> 2, j2 = tid & 3;
    float a1 = 0.f, a2 = 0.f;
#pragma unroll
    for (int w = 0; w < 8; ++w) {
      const float* psp = (const float*)(slds + (w * 32 + sl2) * 36);
      a1 += psp[j2]; a2 += psp[4 + j2];
    }
    const float mu = a1 * 0.0078125f;
    const float var = a2 * 0.0078125f - mu * mu;
    mu_s[tid] = mu;
    rs_s[tid] = rsqrtf(var + 1e-5f);
  }
  __syncthreads();

  float lgv[8], lbv[8];
#pragma unroll
  for (int p = 0; p < 8; ++p) { lgv[p] = lg[q * 8 + p]; lbv[p] = lb[q * 8 + p]; }
#pragma unroll
  for (int j = 0; j < 4; ++j) {
    const int pos = (slot << 2) + j;
    const float mu = mu_s[pos], rs = rs_s[pos];
    float y[8];
#pragma unroll
    for (int p = 0; p < 8; ++p) {
      const float xvj = j == 0 ? xv[p].x : j == 1 ? xv[p].y : j == 2 ? xv[p].z : xv[p].w;
      y[p] = (xvj - mu) * rs * lgv[p] + lbv[p];
    }
    unsigned h0, h1, h2, h3;
    asm("v_cvt_pk_bf16_f32 %0, %1, %2" : "=v"(h0) : "v"(y[0]), "v"(y[1]));
    asm("v_cvt_pk_bf16_f32 %0, %1, %2" : "=v"(h1) : "v"(y[2]), "v"(y[3]));
    asm("v_cvt_pk_bf16_f32 %0, %1, %2" : "=v"(h2) : "v"(y[4]), "v"(y[5]));
    asm("v_cvt_pk_bf16_f32 %0, %1, %2" : "=v"(h3) : "v"(y[6]), "v"(y[7]));
    uint4 v; v.x = h0; v.y = h1; v.z = h2; v.w = h3;
    *(uint4*)(slds + pos * 272 + (q << 4)) = v;
  }
  __syncthreads();
#pragma unroll
  for (int it = 0; it < 4; ++it) {
    const int idx = (it << 9) + tid;
    const int row = idx >> 4, g = idx & 15;
    uint4 v = *(const uint4*)(slds + row * 272 + (g << 4));
    *(uint4*)((unsigned char*)xn + ((size_t)(b * 4096 + hw0 + row)) * 256 + (g << 4)) = v;
  }
}

// ---------------- Persistent bidirectional GRU scan ----------------
// N=8 two-block variant, retried with the CORRECT register budget:
// empirically hipcc treats launch_bounds' 2nd arg as min BLOCKS/CU, so
// (512,2) -> 16 waves/CU -> 128-VGPR cap (fits; r13's (512,4) forced 64 and
// spilled weights to scratch: 1.7GB FETCH). 512 blocks x 512 thr, 8 seqs per
// block, 2 blocks/CU = two independent barrier domains whose MFMA/VALU/LDS
// phases overlap.
// LDS: xbufA @0 (2KB), xbufB @2048, hbufA @4096, hbufB @6144.
__global__ __launch_bounds__(512, 2) void scan_kernel(
    const unsigned short* __restrict__ xn, unsigned short* __restrict__ cat,
    const float* __restrict__ wih0, const float* __restrict__ whh0,
    const float* __restrict__ bih0, const float* __restrict__ bhh0,
    const float* __restrict__ wih1, const float* __restrict__ whh1,
    const float* __restrict__ bih1, const float* __restrict__ bhh1,
    const float* __restrict__ wih2, const float* __restrict__ whh2,
    const float* __restrict__ bih2, const float* __restrict__ bhh2,
    const float* __restrict__ wih3, const float* __restrict__ whh3,
    const float* __restrict__ bih3, const float* __restrict__ bhh3) {
  __shared__ __align__(16) unsigned char lds[8192];
  const int tid = threadIdx.x;
  const int bid = blockIdx.x;
  const int dir = bid >> 7;
  const int grp = bid & 127;
  const int fwd = !(dir & 1);
  const int vert = dir >> 1;
  const int b = grp >> 3;
  const int r0 = (grp & 7) << 3;   // 8-sequence group
  const int wv = tid >> 6;
  const int lane = tid & 63;
  const int l15 = lane & 15;
  const int l7 = lane & 7;
  const int l4 = lane >> 4;

  const float* wih = dir == 0 ? wih0 : dir == 1 ? wih1 : dir == 2 ? wih2 : wih3;
  const float* whh = dir == 0 ? whh0 : dir == 1 ? whh1 : dir == 2 ? whh2 : whh3;
  const float* bih = dir == 0 ? bih0 : dir == 1 ? bih1 : dir == 2 ? bih2 : bih3;
  const float* bhh = dir == 0 ? bhh0 : dir == 1 ? bhh1 : dir == 2 ? bhh2 : bhh3;

  const int ca = (wv << 4) + l15;
  bf16x8 wf[3][2][4];
#pragma unroll
  for (int g = 0; g < 3; ++g) {
    const float sc = g == 2 ? N2LOG2E : NLOG2E;
#pragma unroll
    for (int s = 0; s < 2; ++s) {
      const float* Wp = s ? whh : wih;
#pragma unroll
      for (int kc = 0; kc < 4; ++kc)
        wf[g][s][kc] = pack8s(Wp + (size_t)((g << 7) + ca) * 128 + (kc << 5) + (l4 << 3), sc);
    }
  }
  const int cb = (wv << 4) + (l4 << 2);
  f32x4 br4, bz4, bnx4, bnh4;
  {
    float4 a = *(const float4*)(bih + cb), b2 = *(const float4*)(bhh + cb);
    br4[0] = (a.x + b2.x) * NLOG2E; br4[1] = (a.y + b2.y) * NLOG2E;
    br4[2] = (a.z + b2.z) * NLOG2E; br4[3] = (a.w + b2.w) * NLOG2E;
    a = *(const float4*)(bih + 128 + cb); b2 = *(const float4*)(bhh + 128 + cb);
    bz4[0] = (a.x + b2.x) * NLOG2E; bz4[1] = (a.y + b2.y) * NLOG2E;
    bz4[2] = (a.z + b2.z) * NLOG2E; bz4[3] = (a.w + b2.w) * NLOG2E;
    a = *(const float4*)(bih + 256 + cb);
    bnx4[0] = a.x * N2LOG2E; bnx4[1] = a.y * N2LOG2E;
    bnx4[2] = a.z * N2LOG2E; bnx4[3] = a.w * N2LOG2E;
    b2 = *(const float4*)(bhh + 256 + cb);
    bnh4[0] = b2.x * N2LOG2E; bnh4[1] = b2.y * N2LOG2E;
    bnh4[2] = b2.z * N2LOG2E; bnh4[3] = b2.w * N2LOG2E;
  }

  // Staging: threads 0..127 own (row ss = tid>>4 in [0,8), 16B chunk ck).
  const int ss = tid >> 4, ck = tid & 15;
  const unsigned char* xsp =
      (const unsigned char*)xn +
      (vert ? ((size_t)b << 20) + (size_t)(r0 + ss) * 256 + (ck << 4)
            : ((size_t)(b * 64 + r0 + ss) << 14) + (ck << 4));
  const int xstep = vert ? 16384 : 256;
  const int sdst = (ss * 256 + (ck << 4)) ^ ((ss & 7) << 4);

  const int seq = r0 + l7;
  const int cstep = vert ? 65536 : 1024;
  unsigned char* catp =
      (unsigned char*)cat +
      ((size_t)b * 4096 + (size_t)(vert ? seq : seq * 64)) * 1024 + dir * 256 + (cb << 1) +
      (size_t)(fwd ? 0 : 63) * cstep;
  const int cdelta = fwd ? cstep : -cstep;

  // zero hbufA (@4096, 2KB)
  if (tid < 256) *(unsigned long long*)(lds + 4096 + tid * 8) = 0ull;
  f32x4 hst = {0.f, 0.f, 0.f, 0.f};

  uint4 sX, sY;
  f32x4 grA, gzA, gnxA, grB, gzB, gnxB;
  {
    const unsigned char* xlq =
        (const unsigned char*)xn +
        (vert ? ((size_t)b << 20) + (size_t)(fwd ? 0 : 63) * 16384 + (size_t)seq * 256
              : ((size_t)(b * 64 + seq) << 14) + (size_t)(fwd ? 0 : 63) * 256) +
        (l4 << 4);
    bf16x8 x0[4];
#pragma unroll
    for (int kc = 0; kc < 4; ++kc) x0[kc] = *(const bf16x8*)(xlq + (kc << 6));
    uint4 s1v;
    if (tid < 128) {
      s1v = *(const uint4*)(xsp + (fwd ? 1 : 62) * xstep);
      sX = *(const uint4*)(xsp + (fwd ? 2 : 61) * xstep);
    }
    grA = br4; gzA = bz4; gnxA = bnx4;
#pragma unroll
    for (int kc = 0; kc < 4; ++kc) {
      grA = __builtin_amdgcn_mfma_f32_16x16x32_bf16(wf[0][0][kc], x0[kc], grA, 0, 0, 0);
      gzA = __builtin_amdgcn_mfma_f32_16x16x32_bf16(wf[1][0][kc], x0[kc], gzA, 0, 0, 0);
      gnxA = __builtin_amdgcn_mfma_f32_16x16x32_bf16(wf[2][0][kc], x0[kc], gnxA, 0, 0, 0);
    }
    if (tid < 128) *(uint4*)(lds + 2048 + sdst) = s1v;
  }
  __syncthreads();

#define STEP(TT, HCUR, HNXT, XRD, XWR, XW, XL, GRC, GZC, GNXC, GRN, GZN, GNXN)  \
  {                                                                             \
    bf16x8 ha[4], xa[4];                                                        \
    _Pragma("unroll")                                                           \
    for (int kc = 0; kc < 4; ++kc) {                                            \
      const int base = (l7 * 256 + (kc << 6) + (l4 << 4)) ^ (l7 << 4);          \
      ha[kc] = *(const bf16x8*)(lds + (HCUR) + base);                           \
      xa[kc] = *(const bf16x8*)(lds + (XRD) + base);                            \
    }                                                                           \
    if (tid < 128) {                                                            \
      *(uint4*)(lds + (XWR) + sdst) = XW;                                       \
      const int tl = (TT) + 3 > 63 ? 63 : (TT) + 3;                             \
      XL = *(const uint4*)(xsp + (fwd ? tl : 63 - tl) * xstep);                 \
    }                                                                           \
    f32x4 rh = {0.f, 0.f, 0.f, 0.f}, zh = {0.f, 0.f, 0.f, 0.f}, nh = bnh4;     \
    _Pragma("unroll")                                                           \
    for (int kc = 0; kc < 4; ++kc) {                                            \
      rh = __builtin_amdgcn_mfma_f32_16x16x32_bf16(wf[0][1][kc], ha[kc], rh, 0, 0, 0); \
      zh = __builtin_amdgcn_mfma_f32_16x16x32_bf16(wf[1][1][kc], ha[kc], zh, 0, 0, 0); \
      nh = __builtin_amdgcn_mfma_f32_16x16x32_bf16(wf[2][1][kc], ha[kc], nh, 0, 0, 0); \
    }                                                                           \
    GRN = br4; GZN = bz4; GNXN = bnx4;                                          \
    _Pragma("unroll")                                                           \
    for (int kc = 0; kc < 4; ++kc) {                                            \
      GRN = __builtin_amdgcn_mfma_f32_16x16x32_bf16(wf[0][0][kc], xa[kc], GRN, 0, 0, 0); \
      GZN = __builtin_amdgcn_mfma_f32_16x16x32_bf16(wf[1][0][kc], xa[kc], GZN, 0, 0, 0); \
      GNXN = __builtin_amdgcn_mfma_f32_16x16x32_bf16(wf[2][0][kc], xa[kc], GNXN, 0, 0, 0); \
    }                                                                           \
    f32x4 hnew;                                                                 \
    _Pragma("unroll")                                                           \
    for (int r = 0; r < 4; ++r) {                                               \
      const float er = __builtin_amdgcn_exp2f(GRC[r] + rh[r]);                  \
      const float rr = __builtin_amdgcn_rcpf(1.f + er);                         \
      const float ez = __builtin_amdgcn_exp2f(GZC[r] + zh[r]);                  \
      const float zz = __builtin_amdgcn_rcpf(1.f + ez);                         \
      const float pre = GNXC[r] + rr * nh[r];                                   \
      const float e2 = __builtin_amdgcn_exp2f(pre);                             \
      const float nn = fmaf(2.f, __builtin_amdgcn_rcpf(1.f + e2), -1.f);        \
      hnew[r] = nn + zz * (hst[r] - nn);                                        \
    }                                                                           \
    hst = hnew;                                                                 \
    unsigned hp0, hp1;                                                          \
    asm("v_cvt_pk_bf16_f32 %0, %1, %2" : "=v"(hp0) : "v"(hnew[0]), "v"(hnew[1])); \
    asm("v_cvt_pk_bf16_f32 %0, %1, %2" : "=v"(hp1) : "v"(hnew[2]), "v"(hnew[3])); \
    if (l15 < 8) {                                                              \
      unsigned long long hp = (unsigned long long)hp0 | ((unsigned long long)hp1 << 32); \
      *(unsigned long long*)(lds + (HNXT) + ((l7 * 256 + (cb << 1)) ^ (l7 << 4))) = hp; \
      uint2 v; v.x = hp0; v.y = hp1;                                            \
      *(uint2*)catp = v;                                                        \
    }                                                                           \
    catp += cdelta;                                                             \
    asm volatile("s_waitcnt lgkmcnt(0)" ::: "memory");                          \
    __builtin_amdgcn_s_barrier();                                               \
    asm volatile("" ::: "memory");                                              \
  }

  for (int tt2 = 0; tt2 < 64; tt2 += 2) {
    STEP(tt2, 4096, 6144, 2048, 0, sX, sY, grA, gzA, gnxA, grB, gzB, gnxB);
    STEP(tt2 + 1, 6144, 4096, 0, 2048, sY, sX, grB, gzB, gnxB, grA, gzA, gnxA);
  }
#undef STEP
}

// ---------------- Projection: out = cat[65536,512] @ pwb^T + pb + x ----------------
__global__ __launch_bounds__(512, 4) void proj_kernel(
    const unsigned short* __restrict__ cat, const unsigned short* __restrict__ pwb,
    const float* __restrict__ pb, const float* __restrict__ x,
    float* __restrict__ out) {
  __shared__ __align__(16) unsigned char lds[33280];
  const int tid = threadIdx.x;
  const int bid = blockIdx.x;
  const int row0 = bid << 6;
  const int b = row0 >> 12;
  const int hw0 = row0 & 4095;
  const int wv = tid >> 6, lane = tid & 63, l15 = lane & 15, l4 = lane >> 4;

  const int cc = (wv << 4) + l15;
  bf16x8 wfr[16];
#pragma unroll
  for (int kc = 0; kc < 16; ++kc)
    wfr[kc] = *(const bf16x8*)(pwb + (size_t)cc * 512 + (kc << 5) + (l4 << 3));
  const float pbv = pb[cc];

  f32x4 acc[4];
#pragma unroll
  for (int mt = 0; mt < 4; ++mt) acc[mt] = {pbv, pbv, pbv, pbv};

#pragma unroll
  for (int s = 0; s < 2; ++s) {
#pragma unroll
    for (int it = 0; it < 4; ++it) {
      const int item = tid + (it << 9);
      const int rr = item >> 6, ckk = item & 63;
      uint4 v = *(const uint4*)((const unsigned char*)cat +
                                ((size_t)(row0 + (s << 5) + rr)) * 1024 + ckk * 16);
      *(uint4*)(lds + rr * 1024 + ((ckk ^ (rr & 7)) << 4)) = v;
    }
    __syncthreads();
#pragma unroll
    for (int mh = 0; mh < 2; ++mh) {
      const int mt = (s << 1) + mh;
      const int rl = (mh << 4) + l15;
#pragma unroll
      for (int kc = 0; kc < 16; ++kc) {
        bf16x8 af =
            *(const bf16x8*)(lds + rl * 1024 + ((((kc << 2) + l4) ^ (rl & 7)) << 4));
        acc[mt] = __builtin_amdgcn_mfma_f32_16x16x32_bf16(af, wfr[kc], acc[mt], 0, 0, 0);
      }
    }
    __syncthreads();
  }

#pragma unroll
  for (int mt = 0; mt < 4; ++mt)
#pragma unroll
    for (int j = 0; j < 4; ++j)
      *(float*)(lds + cc * 260 + (((mt << 4) + (l4 << 2) + j) << 2)) = acc[mt][j];
  __syncthreads();
#pragma unroll
  for (int it = 0; it < 16; ++it) {
    const int c = (wv << 4) + it;
    const float v = *(const float*)(lds + c * 260 + (lane << 2));
    const size_t off = (size_t)(b * 128 + c) * 4096 + hw0 + lane;
    out[off] = v + x[off];
  }
}

extern "C" void kernel_launch(void* const* d_in, const int* in_sizes, int n_in,
                              void* d_out, int out_size, void* d_ws, size_t ws_size,
                              hipStream_t stream) {
  const float* x = (const float*)d_in[0];
  const float* lg = (const float*)d_in[1];
  const float* lb = (const float*)d_in[2];
  unsigned short* xn = (unsigned short*)d_ws;                       // 16.8 MB
  unsigned short* cat =
      (unsigned short*)((unsigned char*)d_ws + 16777216);           // 67.1 MB
  unsigned short* pwb =
      (unsigned short*)((unsigned char*)d_ws + 16777216 + 67108864);  // 128 KB

  ln_kernel<<<512, 512, 0, stream>>>(x, lg, lb, xn, (const float*)d_in[19], pwb);
  scan_kernel<<<512, 512, 0, stream>>>(
      xn, cat,
      (const float*)d_in[3], (const float*)d_in[4], (const float*)d_in[5], (const float*)d_in[6],
      (const float*)d_in[7], (const float*)d_in[8], (const float*)d_in[9], (const float*)d_in[10],
      (const float*)d_in[11], (const float*)d_in[12], (const float*)d_in[13], (const float*)d_in[14],
      (const float*)d_in[15], (const float*)d_in[16], (const float*)d_in[17], (const float*)d_in[18]);
  proj_kernel<<<1024, 512, 0, stream>>>(cat, pwb, (const float*)d_in[20], x,
                                        (float*)d_out);
}

// Round 15
// 114.215 us; speedup vs baseline: 5.5349x; 1.5164x over previous
//
#include <hip/hip_runtime.h>

typedef short bf16x8 __attribute__((ext_vector_type(8)));
typedef float f32x4 __attribute__((ext_vector_type(4)));

static __device__ __forceinline__ unsigned short f2bf(float f) {
  unsigned u = __builtin_bit_cast(unsigned, f);
  u += 0x7FFFu + ((u >> 16) & 1u);   // round-nearest-even to bf16
  return (unsigned short)(u >> 16);
}

static __device__ __forceinline__ bf16x8 pack8s(const float* p, float s) {
  float4 a = *(const float4*)p;
  float4 b = *(const float4*)(p + 4);
  bf16x8 r;
  r[0] = (short)f2bf(a.x * s); r[1] = (short)f2bf(a.y * s);
  r[2] = (short)f2bf(a.z * s); r[3] = (short)f2bf(a.w * s);
  r[4] = (short)f2bf(b.x * s); r[5] = (short)f2bf(b.y * s);
  r[6] = (short)f2bf(b.z * s); r[7] = (short)f2bf(b.w * s);
  return r;
}

#define NLOG2E -1.442695040888963f
#define N2LOG2E -2.885390081777927f

// ---------------- LayerNorm (+ fused pw->bf16 prep): x[B,C,H,W] f32 -> xn[B,HW,C] bf16 ----------------
__global__ __launch_bounds__(512, 2) void ln_kernel(
    const float* __restrict__ x, const float* __restrict__ lg,
    const float* __restrict__ lb, unsigned short* __restrict__ xn,
    const float* __restrict__ pw, unsigned short* __restrict__ pwb) {
  __shared__ __align__(16) unsigned char slds[35840];
  float* mu_s = (float*)(slds + 34816);
  float* rs_s = (float*)(slds + 35328);
  const int tid = threadIdx.x;
  const int bid = blockIdx.x;
  if (bid < 128) {  // fused one-time pw f32 -> bf16 (65536 elems)
    const int i = bid * 512 + tid;
    pwb[i] = f2bf(pw[i]);
  }
  const int b = bid >> 5;
  const int hw0 = (bid & 31) << 7;
  const int q = tid >> 5, slot = tid & 31;
  const int lane = tid & 63, wv = tid >> 6;

  const float* xbase = x + ((size_t)b * 128) * 4096 + hw0 + (slot << 2);
  float4 xv[8];
#pragma unroll
  for (int p = 0; p < 8; ++p)
    xv[p] = *(const float4*)(xbase + (size_t)(q * 8 + p) * 4096);

  float s1[4] = {0.f, 0.f, 0.f, 0.f}, s2[4] = {0.f, 0.f, 0.f, 0.f};
#pragma unroll
  for (int p = 0; p < 8; ++p) {
    s1[0] += xv[p].x; s2[0] = fmaf(xv[p].x, xv[p].x, s2[0]);
    s1[1] += xv[p].y; s2[1] = fmaf(xv[p].y, xv[p].y, s2[1]);
    s1[2] += xv[p].z; s2[2] = fmaf(xv[p].z, xv[p].z, s2[2]);
    s1[3] += xv[p].w; s2[3] = fmaf(xv[p].w, xv[p].w, s2[3]);
  }
#pragma unroll
  for (int j = 0; j < 4; ++j) {
    s1[j] += __shfl_xor(s1[j], 32);
    s2[j] += __shfl_xor(s2[j], 32);
  }
  if (lane < 32) {
    float* psp = (float*)(slds + (wv * 32 + slot) * 36);
#pragma unroll
    for (int j = 0; j < 4; ++j) { psp[j] = s1[j]; psp[4 + j] = s2[j]; }
  }
  __syncthreads();
  if (tid < 128) {
    const int sl2 = tid >> 2, j2 = tid & 3;
    float a1 = 0.f, a2 = 0.f;
#pragma unroll
    for (int w = 0; w < 8; ++w) {
      const float* psp = (const float*)(slds + (w * 32 + sl2) * 36);
      a1 += psp[j2]; a2 += psp[4 + j2];
    }
    const float mu = a1 * 0.0078125f;
    const float var = a2 * 0.0078125f - mu * mu;
    mu_s[tid] = mu;
    rs_s[tid] = rsqrtf(var + 1e-5f);
  }
  __syncthreads();

  float lgv[8], lbv[8];
#pragma unroll
  for (int p = 0; p < 8; ++p) { lgv[p] = lg[q * 8 + p]; lbv[p] = lb[q * 8 + p]; }
#pragma unroll
  for (int j = 0; j < 4; ++j) {
    const int pos = (slot << 2) + j;
    const float mu = mu_s[pos], rs = rs_s[pos];
    float y[8];
#pragma unroll
    for (int p = 0; p < 8; ++p) {
      const float xvj = j == 0 ? xv[p].x : j == 1 ? xv[p].y : j == 2 ? xv[p].z : xv[p].w;
      y[p] = (xvj - mu) * rs * lgv[p] + lbv[p];
    }
    unsigned h0, h1, h2, h3;
    asm("v_cvt_pk_bf16_f32 %0, %1, %2" : "=v"(h0) : "v"(y[0]), "v"(y[1]));
    asm("v_cvt_pk_bf16_f32 %0, %1, %2" : "=v"(h1) : "v"(y[2]), "v"(y[3]));
    asm("v_cvt_pk_bf16_f32 %0, %1, %2" : "=v"(h2) : "v"(y[4]), "v"(y[5]));
    asm("v_cvt_pk_bf16_f32 %0, %1, %2" : "=v"(h3) : "v"(y[6]), "v"(y[7]));
    uint4 v; v.x = h0; v.y = h1; v.z = h2; v.w = h3;
    *(uint4*)(slds + pos * 272 + (q << 4)) = v;
  }
  __syncthreads();
#pragma unroll
  for (int it = 0; it < 4; ++it) {
    const int idx = (it << 9) + tid;
    const int row = idx >> 4, g = idx & 15;
    uint4 v = *(const uint4*)(slds + row * 272 + (g << 4));
    *(uint4*)((unsigned char*)xn + ((size_t)(b * 4096 + hw0 + row)) * 256 + (g << 4)) = v;
  }
}

// ---------------- Persistent bidirectional GRU scan ----------------
// Restored round-10 configuration (measured best: 71.6 µs). 8-wave blocks,
// grid 256, 16 sequences/block, full-row XOR swizzle, exp2 weight-prescale,
// x-gate look-ahead, one lgkmcnt-only barrier per step. r11/r13/r14
// established: 1 wave/SIMD (no TLP), 64-VGPR caps (spill), and 2-block
// overlap (regs: ~256 unified/wave -> 1 block/CU) are all worse.
__global__ __launch_bounds__(512, 2) void scan_kernel(
    const unsigned short* __restrict__ xn, unsigned short* __restrict__ cat,
    const float* __restrict__ wih0, const float* __restrict__ whh0,
    const float* __restrict__ bih0, const float* __restrict__ bhh0,
    const float* __restrict__ wih1, const float* __restrict__ whh1,
    const float* __restrict__ bih1, const float* __restrict__ bhh1,
    const float* __restrict__ wih2, const float* __restrict__ whh2,
    const float* __restrict__ bih2, const float* __restrict__ bhh2,
    const float* __restrict__ wih3, const float* __restrict__ whh3,
    const float* __restrict__ bih3, const float* __restrict__ bhh3) {
  __shared__ __align__(16) unsigned char lds[16384];
  const int tid = threadIdx.x;
  const int bid = blockIdx.x;
  const int dir = bid >> 6;
  const int grp = bid & 63;
  const int fwd = !(dir & 1);
  const int vert = dir >> 1;
  const int b = grp >> 2;
  const int r0 = (grp & 3) << 4;
  const int wv = tid >> 6;
  const int lane = tid & 63;
  const int l15 = lane & 15;
  const int l4 = lane >> 4;

  const float* wih = dir == 0 ? wih0 : dir == 1 ? wih1 : dir == 2 ? wih2 : wih3;
  const float* whh = dir == 0 ? whh0 : dir == 1 ? whh1 : dir == 2 ? whh2 : whh3;
  const float* bih = dir == 0 ? bih0 : dir == 1 ? bih1 : dir == 2 ? bih2 : bih3;
  const float* bhh = dir == 0 ? bhh0 : dir == 1 ? bhh1 : dir == 2 ? bhh2 : bhh3;

  const int ca = (wv << 4) + l15;
  bf16x8 wf[3][2][4];
#pragma unroll
  for (int g = 0; g < 3; ++g) {
    const float sc = g == 2 ? N2LOG2E : NLOG2E;
#pragma unroll
    for (int s = 0; s < 2; ++s) {
      const float* Wp = s ? whh : wih;
#pragma unroll
      for (int kc = 0; kc < 4; ++kc)
        wf[g][s][kc] = pack8s(Wp + (size_t)((g << 7) + ca) * 128 + (kc << 5) + (l4 << 3), sc);
    }
  }
  const int cb = (wv << 4) + (l4 << 2);
  f32x4 br4, bz4, bnx4, bnh4;
  {
    float4 a = *(const float4*)(bih + cb), b2 = *(const float4*)(bhh + cb);
    br4[0] = (a.x + b2.x) * NLOG2E; br4[1] = (a.y + b2.y) * NLOG2E;
    br4[2] = (a.z + b2.z) * NLOG2E; br4[3] = (a.w + b2.w) * NLOG2E;
    a = *(const float4*)(bih + 128 + cb); b2 = *(const float4*)(bhh + 128 + cb);
    bz4[0] = (a.x + b2.x) * NLOG2E; bz4[1] = (a.y + b2.y) * NLOG2E;
    bz4[2] = (a.z + b2.z) * NLOG2E; bz4[3] = (a.w + b2.w) * NLOG2E;
    a = *(const float4*)(bih + 256 + cb);
    bnx4[0] = a.x * N2LOG2E; bnx4[1] = a.y * N2LOG2E;
    bnx4[2] = a.z * N2LOG2E; bnx4[3] = a.w * N2LOG2E;
    b2 = *(const float4*)(bhh + 256 + cb);
    bnh4[0] = b2.x * N2LOG2E; bnh4[1] = b2.y * N2LOG2E;
    bnh4[2] = b2.z * N2LOG2E; bnh4[3] = b2.w * N2LOG2E;
  }

  const int ss = tid >> 4, ck = tid & 15;
  const unsigned char* xsp =
      (const unsigned char*)xn +
      (vert ? ((size_t)b << 20) + (size_t)(r0 + ss) * 256 + (ck << 4)
            : ((size_t)(b * 64 + r0 + ss) << 14) + (ck << 4));
  const int xstep = vert ? 16384 : 256;
  const int sdst = (ss * 256 + (ck << 4)) ^ ((ss & 15) << 4);

  const int seq = r0 + l15;
  const int cstep = vert ? 65536 : 1024;
  unsigned char* catp =
      (unsigned char*)cat +
      ((size_t)b * 4096 + (size_t)(vert ? seq : seq * 64)) * 1024 + dir * 256 + (cb << 1) +
      (size_t)(fwd ? 0 : 63) * cstep;
  const int cdelta = fwd ? cstep : -cstep;

  *(unsigned long long*)(lds + 8192 + tid * 8) = 0ull;
  f32x4 hst = {0.f, 0.f, 0.f, 0.f};

  uint4 sX, sY;
  f32x4 grA, gzA, gnxA, grB, gzB, gnxB;
  {
    const unsigned char* xlq =
        (const unsigned char*)xn +
        (vert ? ((size_t)b << 20) + (size_t)(fwd ? 0 : 63) * 16384 + (size_t)seq * 256
              : ((size_t)(b * 64 + seq) << 14) + (size_t)(fwd ? 0 : 63) * 256) +
        (l4 << 4);
    bf16x8 x0[4];
#pragma unroll
    for (int kc = 0; kc < 4; ++kc) x0[kc] = *(const bf16x8*)(xlq + (kc << 6));
    uint4 s1v;
    if (tid < 256) {
      s1v = *(const uint4*)(xsp + (fwd ? 1 : 62) * xstep);
      sX = *(const uint4*)(xsp + (fwd ? 2 : 61) * xstep);
    }
    grA = br4; gzA = bz4; gnxA = bnx4;
#pragma unroll
    for (int kc = 0; kc < 4; ++kc) {
      grA = __builtin_amdgcn_mfma_f32_16x16x32_bf16(wf[0][0][kc], x0[kc], grA, 0, 0, 0);
      gzA = __builtin_amdgcn_mfma_f32_16x16x32_bf16(wf[1][0][kc], x0[kc], gzA, 0, 0, 0);
      gnxA = __builtin_amdgcn_mfma_f32_16x16x32_bf16(wf[2][0][kc], x0[kc], gnxA, 0, 0, 0);
    }
    if (tid < 256) *(uint4*)(lds + 4096 + sdst) = s1v;
  }
  __syncthreads();

#define STEP(TT, HCUR, HNXT, XRD, XWR, XW, XL, GRC, GZC, GNXC, GRN, GZN, GNXN)  \
  {                                                                             \
    bf16x8 ha[4], xa[4];                                                        \
    _Pragma("unroll")                                                           \
    for (int kc = 0; kc < 4; ++kc) {                                            \
      const int base = (l15 * 256 + (kc << 6) + (l4 << 4)) ^ (l15 << 4);        \
      ha[kc] = *(const bf16x8*)(lds + (HCUR) + base);                           \
      xa[kc] = *(const bf16x8*)(lds + (XRD) + base);                            \
    }                                                                           \
    if (tid < 256) {                                                            \
      *(uint4*)(lds + (XWR) + sdst) = XW;                                       \
      const int tl = (TT) + 3 > 63 ? 63 : (TT) + 3;                             \
      XL = *(const uint4*)(xsp + (fwd ? tl : 63 - tl) * xstep);                 \
    }                                                                           \
    f32x4 rh = {0.f, 0.f, 0.f, 0.f}, zh = {0.f, 0.f, 0.f, 0.f}, nh = bnh4;     \
    _Pragma("unroll")                                                           \
    for (int kc = 0; kc < 4; ++kc) {                                            \
      rh = __builtin_amdgcn_mfma_f32_16x16x32_bf16(wf[0][1][kc], ha[kc], rh, 0, 0, 0); \
      zh = __builtin_amdgcn_mfma_f32_16x16x32_bf16(wf[1][1][kc], ha[kc], zh, 0, 0, 0); \
      nh = __builtin_amdgcn_mfma_f32_16x16x32_bf16(wf[2][1][kc], ha[kc], nh, 0, 0, 0); \
    }                                                                           \
    GRN = br4; GZN = bz4; GNXN = bnx4;                                          \
    _Pragma("unroll")                                                           \
    for (int kc = 0; kc < 4; ++kc) {                                            \
      GRN = __builtin_amdgcn_mfma_f32_16x16x32_bf16(wf[0][0][kc], xa[kc], GRN, 0, 0, 0); \
      GZN = __builtin_amdgcn_mfma_f32_16x16x32_bf16(wf[1][0][kc], xa[kc], GZN, 0, 0, 0); \
      GNXN = __builtin_amdgcn_mfma_f32_16x16x32_bf16(wf[2][0][kc], xa[kc], GNXN, 0, 0, 0); \
    }                                                                           \
    f32x4 hnew;                                                                 \
    _Pragma("unroll")                                                           \
    for (int r = 0; r < 4; ++r) {                                               \
      const float er = __builtin_amdgcn_exp2f(GRC[r] + rh[r]);                  \
      const float rr = __builtin_amdgcn_rcpf(1.f + er);                         \
      const float ez = __builtin_amdgcn_exp2f(GZC[r] + zh[r]);                  \
      const float zz = __builtin_amdgcn_rcpf(1.f + ez);                         \
      const float pre = GNXC[r] + rr * nh[r];                                   \
      const float e2 = __builtin_amdgcn_exp2f(pre);                             \
      const float nn = fmaf(2.f, __builtin_amdgcn_rcpf(1.f + e2), -1.f);        \
      hnew[r] = nn + zz * (hst[r] - nn);                                        \
    }                                                                           \
    hst = hnew;                                                                 \
    unsigned hp0, hp1;                                                          \
    asm("v_cvt_pk_bf16_f32 %0, %1, %2" : "=v"(hp0) : "v"(hnew[0]), "v"(hnew[1])); \
    asm("v_cvt_pk_bf16_f32 %0, %1, %2" : "=v"(hp1) : "v"(hnew[2]), "v"(hnew[3])); \
    {                                                                           \
      unsigned long long hp = (unsigned long long)hp0 | ((unsigned long long)hp1 << 32); \
      *(unsigned long long*)(lds + (HNXT) + ((l15 * 256 + (cb << 1)) ^ (l15 << 4))) = hp; \
    }                                                                           \
    {                                                                           \
      uint2 v; v.x = hp0; v.y = hp1;                                            \
      *(uint2*)catp = v;                                                        \
      catp += cdelta;                                                           \
    }                                                                           \
    asm volatile("s_waitcnt lgkmcnt(0)" ::: "memory");                          \
    __builtin_amdgcn_s_barrier();                                               \
    asm volatile("" ::: "memory");                                              \
  }

  for (int tt2 = 0; tt2 < 64; tt2 += 2) {
    STEP(tt2, 8192, 12288, 4096, 0, sX, sY, grA, gzA, gnxA, grB, gzB, gnxB);
    STEP(tt2 + 1, 12288, 8192, 0, 4096, sY, sX, grB, gzB, gnxB, grA, gzA, gnxA);
  }
#undef STEP
}

// ---------------- Projection: out = cat[65536,512] @ pwb^T + pb + x ----------------
__global__ __launch_bounds__(512, 4) void proj_kernel(
    const unsigned short* __restrict__ cat, const unsigned short* __restrict__ pwb,
    const float* __restrict__ pb, const float* __restrict__ x,
    float* __restrict__ out) {
  __shared__ __align__(16) unsigned char lds[33280];
  const int tid = threadIdx.x;
  const int bid = blockIdx.x;
  const int row0 = bid << 6;
  const int b = row0 >> 12;
  const int hw0 = row0 & 4095;
  const int wv = tid >> 6, lane = tid & 63, l15 = lane & 15, l4 = lane >> 4;

  const int cc = (wv << 4) + l15;
  bf16x8 wfr[16];
#pragma unroll
  for (int kc = 0; kc < 16; ++kc)
    wfr[kc] = *(const bf16x8*)(pwb + (size_t)cc * 512 + (kc << 5) + (l4 << 3));
  const float pbv = pb[cc];

  f32x4 acc[4];
#pragma unroll
  for (int mt = 0; mt < 4; ++mt) acc[mt] = {pbv, pbv, pbv, pbv};

#pragma unroll
  for (int s = 0; s < 2; ++s) {
#pragma unroll
    for (int it = 0; it < 4; ++it) {
      const int item = tid + (it << 9);
      const int rr = item >> 6, ckk = item & 63;
      uint4 v = *(const uint4*)((const unsigned char*)cat +
                                ((size_t)(row0 + (s << 5) + rr)) * 1024 + ckk * 16);
      *(uint4*)(lds + rr * 1024 + ((ckk ^ (rr & 7)) << 4)) = v;
    }
    __syncthreads();
#pragma unroll
    for (int mh = 0; mh < 2; ++mh) {
      const int mt = (s << 1) + mh;
      const int rl = (mh << 4) + l15;
#pragma unroll
      for (int kc = 0; kc < 16; ++kc) {
        bf16x8 af =
            *(const bf16x8*)(lds + rl * 1024 + ((((kc << 2) + l4) ^ (rl & 7)) << 4));
        acc[mt] = __builtin_amdgcn_mfma_f32_16x16x32_bf16(af, wfr[kc], acc[mt], 0, 0, 0);
      }
    }
    __syncthreads();
  }

#pragma unroll
  for (int mt = 0; mt < 4; ++mt)
#pragma unroll
    for (int j = 0; j < 4; ++j)
      *(float*)(lds + cc * 260 + (((mt << 4) + (l4 << 2) + j) << 2)) = acc[mt][j];
  __syncthreads();
#pragma unroll
  for (int it = 0; it < 16; ++it) {
    const int c = (wv << 4) + it;
    const float v = *(const float*)(lds + c * 260 + (lane << 2));
    const size_t off = (size_t)(b * 128 + c) * 4096 + hw0 + lane;
    out[off] = v + x[off];
  }
}

extern "C" void kernel_launch(void* const* d_in, const int* in_sizes, int n_in,
                              void* d_out, int out_size, void* d_ws, size_t ws_size,
                              hipStream_t stream) {
  const float* x = (const float*)d_in[0];
  const float* lg = (const float*)d_in[1];
  const float* lb = (const float*)d_in[2];
  unsigned short* xn = (unsigned short*)d_ws;                       // 16.8 MB
  unsigned short* cat =
      (unsigned short*)((unsigned char*)d_ws + 16777216);           // 67.1 MB
  unsigned short* pwb =
      (unsigned short*)((unsigned char*)d_ws + 16777216 + 67108864);  // 128 KB

  ln_kernel<<<512, 512, 0, stream>>>(x, lg, lb, xn, (const float*)d_in[19], pwb);
  scan_kernel<<<256, 512, 0, stream>>>(
      xn, cat,
      (const float*)d_in[3], (const float*)d_in[4], (const float*)d_in[5], (const float*)d_in[6],
      (const float*)d_in[7], (const float*)d_in[8], (const float*)d_in[9], (const float*)d_in[10],
      (const float*)d_in[11], (const float*)d_in[12], (const float*)d_in[13], (const float*)d_in[14],
      (const float*)d_in[15], (const float*)d_in[16], (const float*)d_in[17], (const float*)d_in[18]);
  proj_kernel<<<1024, 512, 0, stream>>>(cat, pwb, (const float*)d_in[20], x,
                                        (float*)d_out);
}

// Round 16
// 101.468 us; speedup vs baseline: 6.2302x; 1.1256x over previous
//
#include <hip/hip_runtime.h>

typedef short bf16x8 __attribute__((ext_vector_type(8)));
typedef float f32x4 __attribute__((ext_vector_type(4)));

static __device__ __forceinline__ unsigned short f2bf(float f) {
  unsigned u = __builtin_bit_cast(unsigned, f);
  u += 0x7FFFu + ((u >> 16) & 1u);   // round-nearest-even to bf16
  return (unsigned short)(u >> 16);
}

static __device__ __forceinline__ bf16x8 pack8s(const float* p, float s) {
  float4 a = *(const float4*)p;
  float4 b = *(const float4*)(p + 4);
  bf16x8 r;
  r[0] = (short)f2bf(a.x * s); r[1] = (short)f2bf(a.y * s);
  r[2] = (short)f2bf(a.z * s); r[3] = (short)f2bf(a.w * s);
  r[4] = (short)f2bf(b.x * s); r[5] = (short)f2bf(b.y * s);
  r[6] = (short)f2bf(b.z * s); r[7] = (short)f2bf(b.w * s);
  return r;
}

#define NLOG2E -1.442695040888963f
#define N2LOG2E -2.885390081777927f

// ---------------- LayerNorm (+ fused pw->fp8 prep): x[B,C,H,W] f32 -> xn[B,HW,C] bf16 ----------------
__global__ __launch_bounds__(512, 2) void ln_kernel(
    const float* __restrict__ x, const float* __restrict__ lg,
    const float* __restrict__ lb, unsigned short* __restrict__ xn,
    const float* __restrict__ pw, unsigned char* __restrict__ pwb) {
  __shared__ __align__(16) unsigned char slds[35840];
  float* mu_s = (float*)(slds + 34816);
  float* rs_s = (float*)(slds + 35328);
  const int tid = threadIdx.x;
  const int bid = blockIdx.x;
  if (bid < 32) {  // fused one-time pw f32 -> fp8 e4m3 (65536 elems, 4/thread)
    const int i = ((bid << 9) + tid) << 2;
    float4 v = *(const float4*)(pw + i);
    unsigned lo8, hi8;
    asm("v_cvt_pk_fp8_f32 %0, %1, %2" : "=v"(lo8) : "v"(v.x), "v"(v.y));
    asm("v_cvt_pk_fp8_f32 %0, %1, %2" : "=v"(hi8) : "v"(v.z), "v"(v.w));
    *(unsigned*)(pwb + i) = (lo8 & 0xffffu) | (hi8 << 16);
  }
  const int b = bid >> 5;
  const int hw0 = (bid & 31) << 7;
  const int q = tid >> 5, slot = tid & 31;
  const int lane = tid & 63, wv = tid >> 6;

  const float* xbase = x + ((size_t)b * 128) * 4096 + hw0 + (slot << 2);
  float4 xv[8];
#pragma unroll
  for (int p = 0; p < 8; ++p)
    xv[p] = *(const float4*)(xbase + (size_t)(q * 8 + p) * 4096);

  float s1[4] = {0.f, 0.f, 0.f, 0.f}, s2[4] = {0.f, 0.f, 0.f, 0.f};
#pragma unroll
  for (int p = 0; p < 8; ++p) {
    s1[0] += xv[p].x; s2[0] = fmaf(xv[p].x, xv[p].x, s2[0]);
    s1[1] += xv[p].y; s2[1] = fmaf(xv[p].y, xv[p].y, s2[1]);
    s1[2] += xv[p].z; s2[2] = fmaf(xv[p].z, xv[p].z, s2[2]);
    s1[3] += xv[p].w; s2[3] = fmaf(xv[p].w, xv[p].w, s2[3]);
  }
#pragma unroll
  for (int j = 0; j < 4; ++j) {
    s1[j] += __shfl_xor(s1[j], 32);
    s2[j] += __shfl_xor(s2[j], 32);
  }
  if (lane < 32) {
    float* psp = (float*)(slds + (wv * 32 + slot) * 36);
#pragma unroll
    for (int j = 0; j < 4; ++j) { psp[j] = s1[j]; psp[4 + j] = s2[j]; }
  }
  __syncthreads();
  if (tid < 128) {
    const int sl2 = tid >> 2, j2 = tid & 3;
    float a1 = 0.f, a2 = 0.f;
#pragma unroll
    for (int w = 0; w < 8; ++w) {
      const float* psp = (const float*)(slds + (w * 32 + sl2) * 36);
      a1 += psp[j2]; a2 += psp[4 + j2];
    }
    const float mu = a1 * 0.0078125f;
    const float var = a2 * 0.0078125f - mu * mu;
    mu_s[tid] = mu;
    rs_s[tid] = rsqrtf(var + 1e-5f);
  }
  __syncthreads();

  float lgv[8], lbv[8];
#pragma unroll
  for (int p = 0; p < 8; ++p) { lgv[p] = lg[q * 8 + p]; lbv[p] = lb[q * 8 + p]; }
#pragma unroll
  for (int j = 0; j < 4; ++j) {
    const int pos = (slot << 2) + j;
    const float mu = mu_s[pos], rs = rs_s[pos];
    float y[8];
#pragma unroll
    for (int p = 0; p < 8; ++p) {
      const float xvj = j == 0 ? xv[p].x : j == 1 ? xv[p].y : j == 2 ? xv[p].z : xv[p].w;
      y[p] = (xvj - mu) * rs * lgv[p] + lbv[p];
    }
    unsigned h0, h1, h2, h3;
    asm("v_cvt_pk_bf16_f32 %0, %1, %2" : "=v"(h0) : "v"(y[0]), "v"(y[1]));
    asm("v_cvt_pk_bf16_f32 %0, %1, %2" : "=v"(h1) : "v"(y[2]), "v"(y[3]));
    asm("v_cvt_pk_bf16_f32 %0, %1, %2" : "=v"(h2) : "v"(y[4]), "v"(y[5]));
    asm("v_cvt_pk_bf16_f32 %0, %1, %2" : "=v"(h3) : "v"(y[6]), "v"(y[7]));
    uint4 v; v.x = h0; v.y = h1; v.z = h2; v.w = h3;
    *(uint4*)(slds + pos * 272 + (q << 4)) = v;
  }
  __syncthreads();
#pragma unroll
  for (int it = 0; it < 4; ++it) {
    const int idx = (it << 9) + tid;
    const int row = idx >> 4, g = idx & 15;
    uint4 v = *(const uint4*)(slds + row * 272 + (g << 4));
    *(uint4*)((unsigned char*)xn + ((size_t)(b * 4096 + hw0 + row)) * 256 + (g << 4)) = v;
  }
}

// ---------------- Persistent bidirectional GRU scan ----------------
// Round-10 structure (measured best). Only change: cat output is quantized
// to fp8 e4m3 (4 channels -> one 4B store). The h recurrence stays bf16, so
// quantization error does NOT compound through time.
__global__ __launch_bounds__(512, 2) void scan_kernel(
    const unsigned short* __restrict__ xn, unsigned char* __restrict__ cat,
    const float* __restrict__ wih0, const float* __restrict__ whh0,
    const float* __restrict__ bih0, const float* __restrict__ bhh0,
    const float* __restrict__ wih1, const float* __restrict__ whh1,
    const float* __restrict__ bih1, const float* __restrict__ bhh1,
    const float* __restrict__ wih2, const float* __restrict__ whh2,
    const float* __restrict__ bih2, const float* __restrict__ bhh2,
    const float* __restrict__ wih3, const float* __restrict__ whh3,
    const float* __restrict__ bih3, const float* __restrict__ bhh3) {
  __shared__ __align__(16) unsigned char lds[16384];
  const int tid = threadIdx.x;
  const int bid = blockIdx.x;
  const int dir = bid >> 6;
  const int grp = bid & 63;
  const int fwd = !(dir & 1);
  const int vert = dir >> 1;
  const int b = grp >> 2;
  const int r0 = (grp & 3) << 4;
  const int wv = tid >> 6;
  const int lane = tid & 63;
  const int l15 = lane & 15;
  const int l4 = lane >> 4;

  const float* wih = dir == 0 ? wih0 : dir == 1 ? wih1 : dir == 2 ? wih2 : wih3;
  const float* whh = dir == 0 ? whh0 : dir == 1 ? whh1 : dir == 2 ? whh2 : whh3;
  const float* bih = dir == 0 ? bih0 : dir == 1 ? bih1 : dir == 2 ? bih2 : bih3;
  const float* bhh = dir == 0 ? bhh0 : dir == 1 ? bhh1 : dir == 2 ? bhh2 : bhh3;

  const int ca = (wv << 4) + l15;
  bf16x8 wf[3][2][4];
#pragma unroll
  for (int g = 0; g < 3; ++g) {
    const float sc = g == 2 ? N2LOG2E : NLOG2E;
#pragma unroll
    for (int s = 0; s < 2; ++s) {
      const float* Wp = s ? whh : wih;
#pragma unroll
      for (int kc = 0; kc < 4; ++kc)
        wf[g][s][kc] = pack8s(Wp + (size_t)((g << 7) + ca) * 128 + (kc << 5) + (l4 << 3), sc);
    }
  }
  const int cb = (wv << 4) + (l4 << 2);
  f32x4 br4, bz4, bnx4, bnh4;
  {
    float4 a = *(const float4*)(bih + cb), b2 = *(const float4*)(bhh + cb);
    br4[0] = (a.x + b2.x) * NLOG2E; br4[1] = (a.y + b2.y) * NLOG2E;
    br4[2] = (a.z + b2.z) * NLOG2E; br4[3] = (a.w + b2.w) * NLOG2E;
    a = *(const float4*)(bih + 128 + cb); b2 = *(const float4*)(bhh + 128 + cb);
    bz4[0] = (a.x + b2.x) * NLOG2E; bz4[1] = (a.y + b2.y) * NLOG2E;
    bz4[2] = (a.z + b2.z) * NLOG2E; bz4[3] = (a.w + b2.w) * NLOG2E;
    a = *(const float4*)(bih + 256 + cb);
    bnx4[0] = a.x * N2LOG2E; bnx4[1] = a.y * N2LOG2E;
    bnx4[2] = a.z * N2LOG2E; bnx4[3] = a.w * N2LOG2E;
    b2 = *(const float4*)(bhh + 256 + cb);
    bnh4[0] = b2.x * N2LOG2E; bnh4[1] = b2.y * N2LOG2E;
    bnh4[2] = b2.z * N2LOG2E; bnh4[3] = b2.w * N2LOG2E;
  }

  const int ss = tid >> 4, ck = tid & 15;
  const unsigned char* xsp =
      (const unsigned char*)xn +
      (vert ? ((size_t)b << 20) + (size_t)(r0 + ss) * 256 + (ck << 4)
            : ((size_t)(b * 64 + r0 + ss) << 14) + (ck << 4));
  const int xstep = vert ? 16384 : 256;
  const int sdst = (ss * 256 + (ck << 4)) ^ ((ss & 15) << 4);

  const int seq = r0 + l15;
  const int cstep = vert ? 32768 : 512;
  unsigned char* catp =
      cat + ((size_t)b * 4096 + (size_t)(vert ? seq : seq * 64)) * 512 + dir * 128 + cb +
      (size_t)(fwd ? 0 : 63) * cstep;
  const int cdelta = fwd ? cstep : -cstep;

  *(unsigned long long*)(lds + 8192 + tid * 8) = 0ull;
  f32x4 hst = {0.f, 0.f, 0.f, 0.f};

  uint4 sX, sY;
  f32x4 grA, gzA, gnxA, grB, gzB, gnxB;
  {
    const unsigned char* xlq =
        (const unsigned char*)xn +
        (vert ? ((size_t)b << 20) + (size_t)(fwd ? 0 : 63) * 16384 + (size_t)seq * 256
              : ((size_t)(b * 64 + seq) << 14) + (size_t)(fwd ? 0 : 63) * 256) +
        (l4 << 4);
    bf16x8 x0[4];
#pragma unroll
    for (int kc = 0; kc < 4; ++kc) x0[kc] = *(const bf16x8*)(xlq + (kc << 6));
    uint4 s1v;
    if (tid < 256) {
      s1v = *(const uint4*)(xsp + (fwd ? 1 : 62) * xstep);
      sX = *(const uint4*)(xsp + (fwd ? 2 : 61) * xstep);
    }
    grA = br4; gzA = bz4; gnxA = bnx4;
#pragma unroll
    for (int kc = 0; kc < 4; ++kc) {
      grA = __builtin_amdgcn_mfma_f32_16x16x32_bf16(wf[0][0][kc], x0[kc], grA, 0, 0, 0);
      gzA = __builtin_amdgcn_mfma_f32_16x16x32_bf16(wf[1][0][kc], x0[kc], gzA, 0, 0, 0);
      gnxA = __builtin_amdgcn_mfma_f32_16x16x32_bf16(wf[2][0][kc], x0[kc], gnxA, 0, 0, 0);
    }
    if (tid < 256) *(uint4*)(lds + 4096 + sdst) = s1v;
  }
  __syncthreads();

#define STEP(TT, HCUR, HNXT, XRD, XWR, XW, XL, GRC, GZC, GNXC, GRN, GZN, GNXN)  \
  {                                                                             \
    bf16x8 ha[4], xa[4];                                                        \
    _Pragma("unroll")                                                           \
    for (int kc = 0; kc < 4; ++kc) {                                            \
      const int base = (l15 * 256 + (kc << 6) + (l4 << 4)) ^ (l15 << 4);        \
      ha[kc] = *(const bf16x8*)(lds + (HCUR) + base);                           \
      xa[kc] = *(const bf16x8*)(lds + (XRD) + base);                            \
    }                                                                           \
    if (tid < 256) {                                                            \
      *(uint4*)(lds + (XWR) + sdst) = XW;                                       \
      const int tl = (TT) + 3 > 63 ? 63 : (TT) + 3;                             \
      XL = *(const uint4*)(xsp + (fwd ? tl : 63 - tl) * xstep);                 \
    }                                                                           \
    f32x4 rh = {0.f, 0.f, 0.f, 0.f}, zh = {0.f, 0.f, 0.f, 0.f}, nh = bnh4;     \
    _Pragma("unroll")                                                           \
    for (int kc = 0; kc < 4; ++kc) {                                            \
      rh = __builtin_amdgcn_mfma_f32_16x16x32_bf16(wf[0][1][kc], ha[kc], rh, 0, 0, 0); \
      zh = __builtin_amdgcn_mfma_f32_16x16x32_bf16(wf[1][1][kc], ha[kc], zh, 0, 0, 0); \
      nh = __builtin_amdgcn_mfma_f32_16x16x32_bf16(wf[2][1][kc], ha[kc], nh, 0, 0, 0); \
    }                                                                           \
    GRN = br4; GZN = bz4; GNXN = bnx4;                                          \
    _Pragma("unroll")                                                           \
    for (int kc = 0; kc < 4; ++kc) {                                            \
      GRN = __builtin_amdgcn_mfma_f32_16x16x32_bf16(wf[0][0][kc], xa[kc], GRN, 0, 0, 0); \
      GZN = __builtin_amdgcn_mfma_f32_16x16x32_bf16(wf[1][0][kc], xa[kc], GZN, 0, 0, 0); \
      GNXN = __builtin_amdgcn_mfma_f32_16x16x32_bf16(wf[2][0][kc], xa[kc], GNXN, 0, 0, 0); \
    }                                                                           \
    f32x4 hnew;                                                                 \
    _Pragma("unroll")                                                           \
    for (int r = 0; r < 4; ++r) {                                               \
      const float er = __builtin_amdgcn_exp2f(GRC[r] + rh[r]);                  \
      const float rr = __builtin_amdgcn_rcpf(1.f + er);                         \
      const float ez = __builtin_amdgcn_exp2f(GZC[r] + zh[r]);                  \
      const float zz = __builtin_amdgcn_rcpf(1.f + ez);                         \
      const float pre = GNXC[r] + rr * nh[r];                                   \
      const float e2 = __builtin_amdgcn_exp2f(pre);                             \
      const float nn = fmaf(2.f, __builtin_amdgcn_rcpf(1.f + e2), -1.f);        \
      hnew[r] = nn + zz * (hst[r] - nn);                                        \
    }                                                                           \
    hst = hnew;                                                                 \
    unsigned hp0, hp1;                                                          \
    asm("v_cvt_pk_bf16_f32 %0, %1, %2" : "=v"(hp0) : "v"(hnew[0]), "v"(hnew[1])); \
    asm("v_cvt_pk_bf16_f32 %0, %1, %2" : "=v"(hp1) : "v"(hnew[2]), "v"(hnew[3])); \
    {                                                                           \
      unsigned long long hp = (unsigned long long)hp0 | ((unsigned long long)hp1 << 32); \
      *(unsigned long long*)(lds + (HNXT) + ((l15 * 256 + (cb << 1)) ^ (l15 << 4))) = hp; \
    }                                                                           \
    {                                                                           \
      unsigned lo8, hi8;                                                        \
      asm("v_cvt_pk_fp8_f32 %0, %1, %2" : "=v"(lo8) : "v"(hnew[0]), "v"(hnew[1])); \
      asm("v_cvt_pk_fp8_f32 %0, %1, %2" : "=v"(hi8) : "v"(hnew[2]), "v"(hnew[3])); \
      *(unsigned*)catp = (lo8 & 0xffffu) | (hi8 << 16);                         \
      catp += cdelta;                                                           \
    }                                                                           \
    asm volatile("s_waitcnt lgkmcnt(0)" ::: "memory");                          \
    __builtin_amdgcn_s_barrier();                                               \
    asm volatile("" ::: "memory");                                              \
  }

  for (int tt2 = 0; tt2 < 64; tt2 += 2) {
    STEP(tt2, 8192, 12288, 4096, 0, sX, sY, grA, gzA, gnxA, grB, gzB, gnxB);
    STEP(tt2 + 1, 12288, 8192, 0, 4096, sY, sX, grB, gzB, gnxB, grA, gzA, gnxA);
  }
#undef STEP
}

// ---------------- Projection: out = cat[65536,512]fp8 @ pwb^T(fp8) + pb + x ----------------
// fp8 e4m3 MFMA (16x16x32_fp8_fp8, i64 operands = 8 fp8/lane, same k-mapping
// as bf16). cat staged in two 16KB stages; A-frag 8B reads with 16B-chunk XOR
// swizzle (2-way free). Epilogue transpose unchanged (f32, 260B pitch).
__global__ __launch_bounds__(512, 4) void proj_kernel(
    const unsigned char* __restrict__ cat, const unsigned char* __restrict__ pwb,
    const float* __restrict__ pb, const float* __restrict__ x,
    float* __restrict__ out) {
  __shared__ __align__(16) unsigned char lds[33280];
  const int tid = threadIdx.x;
  const int bid = blockIdx.x;
  const int row0 = bid << 6;
  const int b = row0 >> 12;
  const int hw0 = row0 & 4095;
  const int wv = tid >> 6, lane = tid & 63, l15 = lane & 15, l4 = lane >> 4;

  // B-fragments: lane's n-col = cc, k = kc*32 + l4*8 + 0..7 (fp8 direct).
  const int cc = (wv << 4) + l15;
  long wfr[16];
#pragma unroll
  for (int kc = 0; kc < 16; ++kc)
    wfr[kc] = *(const long*)(pwb + (size_t)cc * 512 + (kc << 5) + (l4 << 3));
  const float pbv = pb[cc];

  f32x4 acc[4];
#pragma unroll
  for (int mt = 0; mt < 4; ++mt) acc[mt] = {pbv, pbv, pbv, pbv};

#pragma unroll
  for (int s = 0; s < 2; ++s) {
    // stage rows s*32 .. s*32+31 (16 KB, 512B/row fp8)
#pragma unroll
    for (int it = 0; it < 2; ++it) {
      const int item = tid + (it << 9);
      const int rr = item >> 5, ckk = item & 31;
      uint4 v = *(const uint4*)(cat + ((size_t)(row0 + (s << 5) + rr)) * 512 + (ckk << 4));
      *(uint4*)(lds + rr * 512 + ((ckk ^ (rr & 7)) << 4)) = v;
    }
    __syncthreads();
#pragma unroll
    for (int mh = 0; mh < 2; ++mh) {
      const int mt = (s << 1) + mh;
      const int rl = (mh << 4) + l15;  // local row in stage
#pragma unroll
      for (int kc = 0; kc < 16; ++kc) {
        const int g8 = (kc << 2) + l4;  // 8B granule 0..63
        long af = *(const long*)(lds + rl * 512 +
                                 ((((g8 >> 1) ^ (rl & 7)) << 4) | ((g8 & 1) << 3)));
        acc[mt] = __builtin_amdgcn_mfma_f32_16x16x32_fp8_fp8(af, wfr[kc], acc[mt], 0, 0, 0);
      }
    }
    __syncthreads();
  }

  // Transpose epilogue: tr[c][hw] f32, pitch 260 B (bank-conflict-free).
#pragma unroll
  for (int mt = 0; mt < 4; ++mt)
#pragma unroll
    for (int j = 0; j < 4; ++j)
      *(float*)(lds + cc * 260 + (((mt << 4) + (l4 << 2) + j) << 2)) = acc[mt][j];
  __syncthreads();
#pragma unroll
  for (int it = 0; it < 16; ++it) {
    const int c = (wv << 4) + it;
    const float v = *(const float*)(lds + c * 260 + (lane << 2));
    const size_t off = (size_t)(b * 128 + c) * 4096 + hw0 + lane;
    out[off] = v + x[off];
  }
}

extern "C" void kernel_launch(void* const* d_in, const int* in_sizes, int n_in,
                              void* d_out, int out_size, void* d_ws, size_t ws_size,
                              hipStream_t stream) {
  const float* x = (const float*)d_in[0];
  const float* lg = (const float*)d_in[1];
  const float* lb = (const float*)d_in[2];
  unsigned short* xn = (unsigned short*)d_ws;                         // 16.8 MB
  unsigned char* cat = (unsigned char*)d_ws + 16777216;               // 33.5 MB fp8
  unsigned char* pwb = (unsigned char*)d_ws + 16777216 + 33554432;    // 64 KB fp8

  ln_kernel<<<512, 512, 0, stream>>>(x, lg, lb, xn, (const float*)d_in[19], pwb);
  scan_kernel<<<256, 512, 0, stream>>>(
      xn, cat,
      (const float*)d_in[3], (const float*)d_in[4], (const float*)d_in[5], (const float*)d_in[6],
      (const float*)d_in[7], (const float*)d_in[8], (const float*)d_in[9], (const float*)d_in[10],
      (const float*)d_in[11], (const float*)d_in[12], (const float*)d_in[13], (const float*)d_in[14],
      (const float*)d_in[15], (const float*)d_in[16], (const float*)d_in[17], (const float*)d_in[18]);
  proj_kernel<<<1024, 512, 0, stream>>>(cat, pwb, (const float*)d_in[20], x,
                                        (float*)d_out);
}